// Round 1
// baseline (451.536 us; speedup 1.0000x reference)
//
#include <hip/hip_runtime.h>

#define HW (512*512)
#define NB 8
#define NC 14
#define NPIX (NB*HW)
#define DELTA_F 0.7f
#define FUS_F 0.01f

// ws layout (4-byte units): [0..195] A (float), [196..391] cm (uint),
// [392] ce_sum (float), [393] bl_sum (float)

__global__ __launch_bounds__(256) void main_pass(
    const float* __restrict__ y_pred, const float* __restrict__ weight,
    const int* __restrict__ y_true, const int* __restrict__ backlabel,
    float* __restrict__ gA, unsigned* __restrict__ gcm, float* __restrict__ gsums)
{
    __shared__ float    sA[NC * NC];
    __shared__ unsigned sCM[NC * NC];
    __shared__ float    sW[NC];

    const int tid = threadIdx.x;
    for (int j = tid; j < NC * NC; j += blockDim.x) { sA[j] = 0.0f; sCM[j] = 0u; }
    if (tid < NC) sW[tid] = weight[tid];
    __syncthreads();

    float ceAcc = 0.0f, blAcc = 0.0f;

    const int nquad  = NPIX / 4;
    const int stride = gridDim.x * blockDim.x;
    for (int q = blockIdx.x * blockDim.x + tid; q < nquad; q += stride) {
        const int b   = q / (HW / 4);
        const int hw4 = q - b * (HW / 4);
        const int pix = b * HW + hw4 * 4;

        // 14 channel-strided float4 loads (each coalesced across the wave)
        float x[NC][4];
        #pragma unroll
        for (int c = 0; c < NC; ++c) {
            const float4 v = *reinterpret_cast<const float4*>(
                y_pred + (size_t)(b * NC + c) * HW + (size_t)hw4 * 4);
            x[c][0] = v.x; x[c][1] = v.y; x[c][2] = v.z; x[c][3] = v.w;
        }
        const int4 t4  = *reinterpret_cast<const int4*>(y_true + pix);
        const int4 bb4 = *reinterpret_cast<const int4*>(backlabel + pix);
        const int ts[4] = { t4.x, t4.y, t4.z, t4.w };
        const int bs[4] = { bb4.x, bb4.y, bb4.z, bb4.w };

        #pragma unroll
        for (int j = 0; j < 4; ++j) {
            int t = ts[j];
            t = (t < 0) ? 0 : ((t >= NC) ? (NC - 1) : t);   // safety clamp (inputs are in [0,14))
            const int bb = bs[j];
            const float bl = (bb == 0) ? 0.4f : (float)bb;

            // max + argmax (first-occurrence via strict >) + select x[t] statically
            float m  = x[0][j];
            int   am = 0;
            float xt = x[0][j];
            #pragma unroll
            for (int c = 1; c < NC; ++c) {
                const float xc = x[c][j];
                if (xc > m) { m = xc; am = c; }
                xt = (c == t) ? xc : xt;    // static register index, runtime select
            }

            float e[NC];
            float s = 0.0f;
            #pragma unroll
            for (int c = 0; c < NC; ++c) { e[c] = __expf(x[c][j] - m); s += e[c]; }
            const float inv = 1.0f / s;
            const float lse = __logf(s);

            const float nll = -(xt - m - lse);
            ceAcc += sW[t] * nll * bl;
            blAcc += bl;

            atomicAdd(&sCM[t * NC + am], 1u);
            const float blinv = bl * inv;
            #pragma unroll
            for (int c = 0; c < NC; ++c)
                unsafeAtomicAdd(&sA[t * NC + c], blinv * e[c]);
        }
    }
    __syncthreads();

    // flush block-local accumulators
    for (int j = tid; j < NC * NC; j += blockDim.x) {
        const float a = sA[j];
        if (a != 0.0f) unsafeAtomicAdd(&gA[j], a);
        const unsigned cmv = sCM[j];
        if (cmv) atomicAdd(&gcm[j], cmv);
    }

    // wave-reduce scalar partials, one atomic per wave
    #pragma unroll
    for (int o = 32; o > 0; o >>= 1) {
        ceAcc += __shfl_down(ceAcc, o, 64);
        blAcc += __shfl_down(blAcc, o, 64);
    }
    if ((tid & 63) == 0) {
        unsafeAtomicAdd(&gsums[0], ceAcc);
        unsafeAtomicAdd(&gsums[1], blAcc);
    }
}

__global__ __launch_bounds__(256) void finalize_pass(
    const float* __restrict__ gA, const unsigned* __restrict__ gcm,
    const float* __restrict__ gsums, const float* __restrict__ wei_confus,
    float* __restrict__ out)
{
    __shared__ float cinv[NC];
    __shared__ float red[4];
    const int tid = threadIdx.x;

    if (tid < NC) {
        float col = 0.0f;
        for (int r = 0; r < NC; ++r) col += (float)gcm[r * NC + tid];
        cinv[tid] = (col == 0.0f) ? 1.0f : (1.0f / col);
    }
    __syncthreads();

    float part = 0.0f;
    for (int idx = tid; idx < NC * NC; idx += blockDim.x) {
        const int t = idx / NC;
        const int c = idx - t * NC;
        // wc[c][t] = (wei_confus[c][t] + 0.01 * cm[c][t] / col[t]) / 1.01
        const float wc = (wei_confus[c * NC + t]
                          + FUS_F * (float)gcm[c * NC + t] * cinv[t]) * (1.0f / (1.0f + FUS_F));
        part += gA[idx] * wc;
    }
    #pragma unroll
    for (int o = 32; o > 0; o >>= 1) part += __shfl_down(part, o, 64);
    if ((tid & 63) == 0) red[tid >> 6] = part;
    __syncthreads();

    if (tid == 0) {
        const float tot = red[0] + red[1] + red[2] + red[3];
        const float ce  = gsums[0];
        const float bls = gsums[1];
        out[0] = (bls * (1.0f / NC) - tot * (1.0f / NC) + DELTA_F * ce) * (1.0f / (float)NPIX);
    }
}

extern "C" void kernel_launch(void* const* d_in, const int* in_sizes, int n_in,
                              void* d_out, int out_size, void* d_ws, size_t ws_size,
                              hipStream_t stream) {
    const float* y_pred     = (const float*)d_in[0];
    const float* wei_confus = (const float*)d_in[1];
    const float* weight     = (const float*)d_in[2];
    const int*   y_true     = (const int*)d_in[3];
    const int*   backlabel  = (const int*)d_in[4];

    float*    gA    = (float*)d_ws;
    unsigned* gcm   = (unsigned*)((char*)d_ws + 196 * 4);
    float*    gsums = (float*)((char*)d_ws + 392 * 4);

    hipMemsetAsync(d_ws, 0, 394 * 4, stream);

    // 2048 blocks x 256 threads x 4 pixels/thread == 2,097,152 pixels exactly
    main_pass<<<2048, 256, 0, stream>>>(y_pred, weight, y_true, backlabel, gA, gcm, gsums);
    finalize_pass<<<1, 256, 0, stream>>>(gA, gcm, gsums, wei_confus, (float*)out_size ? (float*)d_out : (float*)d_out);
}